// Round 7
// baseline (27.108 us; speedup 1.0000x reference)
//
#include <hip/hip_runtime.h>
#include <hip/hip_fp16.h>
#include <math.h>

#define B 4
#define S 4096
#define N 4096
#define BLK1 128
#define SPT 8             // grid points per thread
#define NCHUNK 128
#define CSIZE 32          // N / NCHUNK, staged in one pass
#define BLK2 256
#define CSPLIT 8          // kernel2a groups
#define CPG (NCHUNK / CSPLIT)
#define INF 3.4e38f

// Kernel 1: each thread owns SPT grid points; block stages its 32-point cloud
// chunk (both clouds) into LDS packed as float4{y, 0.5|y|^2}; inner loop =
// broadcast ds_read_b128 + FMA/min3 Gram chains t = hy - x.y.
// Writes u = max(hx + min t, 0) as fp16 partials [cloud][chunk][B][S].
__global__ __launch_bounds__(BLK1, 4) void sdf_partial_min(
    const float* __restrict__ grid,   // [B,S,3]
    const float* __restrict__ gts,    // [B,N,3]
    const float* __restrict__ preds,  // [B,N,3]
    __half* __restrict__ partial)     // [2][NCHUNK][B][S]
{
    __shared__ float4 raw[2 * CSIZE * 3 / 4];   // 48 float4: p then g
    __shared__ float4 lp[CSIZE];
    __shared__ float4 lg[CSIZE];

    const int tid   = threadIdx.x;
    const int stile = blockIdx.x;            // 4 tiles of 1024 s
    const int chunk = blockIdx.y;
    const int b     = blockIdx.z;

    const int s0 = stile * (BLK1 * SPT) + tid;   // gp i at s0 + i*BLK1

    float x0[SPT], x1[SPT], x2[SPT], hx[SPT];
    #pragma unroll
    for (int i = 0; i < SPT; ++i) {
        const float* xp = grid + ((size_t)b * S + s0 + i * BLK1) * 3;
        x0[i] = -xp[0]; x1[i] = -xp[1]; x2[i] = -xp[2];
        hx[i] = 0.5f * (x0[i] * x0[i] + x1[i] * x1[i] + x2[i] * x2[i]);
    }

    // stage raw chunk (32 pts * 3 floats = 24 float4 per cloud)
    {
        const int n0 = chunk * CSIZE;
        const float4* pv = (const float4*)(preds + ((size_t)b * N + n0) * 3);
        const float4* gv = (const float4*)(gts   + ((size_t)b * N + n0) * 3);
        if (tid < CSIZE * 3 / 4)
            raw[tid] = pv[tid];
        else if (tid < CSIZE * 3 / 2)
            raw[tid] = gv[tid - CSIZE * 3 / 4];
    }
    __syncthreads();
    // pack with hy (3-stride float reads from LDS: conflict-free, 3 coprime 32)
    if (tid < CSIZE) {
        const float* rp = (const float*)raw;
        float a = rp[3 * tid], c1 = rp[3 * tid + 1], c2 = rp[3 * tid + 2];
        lp[tid] = make_float4(a, c1, c2, 0.5f * (a * a + c1 * c1 + c2 * c2));
    } else if (tid < 2 * CSIZE) {
        const int j = tid - CSIZE;
        const float* rg = (const float*)raw + CSIZE * 3;
        float a = rg[3 * j], c1 = rg[3 * j + 1], c2 = rg[3 * j + 2];
        lg[j] = make_float4(a, c1, c2, 0.5f * (a * a + c1 * c1 + c2 * c2));
    }
    __syncthreads();

    float accp[SPT], accg[SPT];
    #pragma unroll
    for (int i = 0; i < SPT; ++i) { accp[i] = INF; accg[i] = INF; }

    #pragma unroll 2
    for (int j = 0; j < CSIZE; j += 4) {
        const float4 p0 = lp[j], p1 = lp[j + 1], p2 = lp[j + 2], p3 = lp[j + 3];
        #pragma unroll
        for (int i = 0; i < SPT; ++i) {
            float a0 = fmaf(x0[i], p0.x, fmaf(x1[i], p0.y, fmaf(x2[i], p0.z, p0.w)));
            float a1 = fmaf(x0[i], p1.x, fmaf(x1[i], p1.y, fmaf(x2[i], p1.z, p1.w)));
            float a2 = fmaf(x0[i], p2.x, fmaf(x1[i], p2.y, fmaf(x2[i], p2.z, p2.w)));
            float a3 = fmaf(x0[i], p3.x, fmaf(x1[i], p3.y, fmaf(x2[i], p3.z, p3.w)));
            accp[i] = fminf(fminf(accp[i], fminf(a0, a1)), fminf(a2, a3));
        }
        const float4 g0 = lg[j], g1 = lg[j + 1], g2 = lg[j + 2], g3 = lg[j + 3];
        #pragma unroll
        for (int i = 0; i < SPT; ++i) {
            float a0 = fmaf(x0[i], g0.x, fmaf(x1[i], g0.y, fmaf(x2[i], g0.z, g0.w)));
            float a1 = fmaf(x0[i], g1.x, fmaf(x1[i], g1.y, fmaf(x2[i], g1.z, g1.w)));
            float a2 = fmaf(x0[i], g2.x, fmaf(x1[i], g2.y, fmaf(x2[i], g2.z, g2.w)));
            float a3 = fmaf(x0[i], g3.x, fmaf(x1[i], g3.y, fmaf(x2[i], g3.z, g3.w)));
            accg[i] = fminf(fminf(accg[i], fminf(a0, a1)), fminf(a2, a3));
        }
    }

    #pragma unroll
    for (int i = 0; i < SPT; ++i) {
        const size_t sidx = (size_t)b * S + s0 + i * BLK1;
        const size_t cidx = (size_t)chunk * (B * S) + sidx;
        partial[cidx] = __float2half(fmaxf(hx[i] + accp[i], 0.f));
        partial[(size_t)NCHUNK * (B * S) + cidx] = __float2half(fmaxf(hx[i] + accg[i], 0.f));
    }
}

// Kernel 2a: per (tile,b,cs): min over CPG chunks (coalesced fp16 reads),
// write fp32 part2[cs][cloud][b][s].
__global__ __launch_bounds__(BLK2) void sdf_reduce_a(
    const __half* __restrict__ partial, float* __restrict__ part2)
{
    const int tile = blockIdx.x;
    const int b    = blockIdx.y;
    const int cs   = blockIdx.z;
    const int tid  = threadIdx.x;
    const int s    = tile * BLK2 + tid;

    const size_t bs = (size_t)B * S;
    const size_t base = (size_t)b * S + s;

    float mp = INF, mg = INF;
    #pragma unroll
    for (int c = 0; c < CPG; ++c) {
        const size_t cidx = (size_t)(cs * CPG + c) * bs + base;
        mp = fminf(mp, __half2float(partial[cidx]));
        mg = fminf(mg, __half2float(partial[(size_t)NCHUNK * bs + cidx]));
    }
    part2[(size_t)(cs * 2 + 0) * bs + base] = mp;
    part2[(size_t)(cs * 2 + 1) * bs + base] = mg;
}

// Kernel 2b: per (tile,b): min over CSPLIT groups, d = sqrt(2u), |diff|,
// block-sum -> pb[b*ntile + tile].
__global__ __launch_bounds__(BLK2) void sdf_reduce_b(
    const float* __restrict__ part2, float* __restrict__ pb)
{
    const int tile = blockIdx.x;
    const int b    = blockIdx.y;
    const int tid  = threadIdx.x;
    const int s    = tile * BLK2 + tid;

    const size_t bs = (size_t)B * S;
    const size_t base = (size_t)b * S + s;

    float mp = INF, mg = INF;
    #pragma unroll
    for (int cs = 0; cs < CSPLIT; ++cs) {
        mp = fminf(mp, part2[(size_t)(cs * 2 + 0) * bs + base]);
        mg = fminf(mg, part2[(size_t)(cs * 2 + 1) * bs + base]);
    }

    float v = fabsf(sqrtf(fmaxf(2.f * mp, 0.f)) - sqrtf(fmaxf(2.f * mg, 0.f)));

    #pragma unroll
    for (int off = 32; off > 0; off >>= 1)
        v += __shfl_down(v, off, 64);

    __shared__ float wsum[BLK2 / 64];
    if ((tid & 63) == 0) wsum[tid >> 6] = v;
    __syncthreads();
    if (tid == 0) {
        float t = 0.f;
        #pragma unroll
        for (int w = 0; w < BLK2 / 64; ++w) t += wsum[w];
        pb[b * gridDim.x + tile] = t;
    }
}

// Kernel 3: final tiny reduction (ntile=16 partials per batch).
__global__ __launch_bounds__(64) void sdf_final(
    const float* __restrict__ pb, float* __restrict__ out)
{
    const int tid = threadIdx.x;
    const int ntile = S / BLK2;   // 16
    float v = (tid < B * ntile) ? pb[tid] : 0.f;
    #pragma unroll
    for (int off = 8; off > 0; off >>= 1)
        v += __shfl_down(v, off, 16);
    if (tid < B * ntile && (tid & 15) == 0)
        out[tid / 16] = v / (float)S;
}

extern "C" void kernel_launch(void* const* d_in, const int* in_sizes, int n_in,
                              void* d_out, int out_size, void* d_ws, size_t ws_size,
                              hipStream_t stream) {
    const float* grid  = (const float*)d_in[0];
    const float* gts   = (const float*)d_in[1];
    const float* preds = (const float*)d_in[2];
    float* out = (float*)d_out;

    // ws layout (ws is ~256 MB):
    // partial fp16: 2*NCHUNK*B*S*2B = 8.4 MB at offset 0
    // part2  fp32 : 2*CSPLIT*B*S*4B = 1 MB  at offset 16 MB
    // pb          : 64 floats       at offset 32 MB
    __half* partial = (__half*)d_ws;
    float*  part2   = (float*)((char*)d_ws + (16u << 20));
    float*  pb      = (float*)((char*)d_ws + (32u << 20));

    dim3 g1(S / (BLK1 * SPT), NCHUNK, B);    // (4, 128, 4) = 2048 blocks
    sdf_partial_min<<<g1, BLK1, 0, stream>>>(grid, gts, preds, partial);

    dim3 g2a(S / BLK2, B, CSPLIT);           // (16, 4, 8) = 512 blocks
    sdf_reduce_a<<<g2a, BLK2, 0, stream>>>(partial, part2);

    dim3 g2b(S / BLK2, B);                   // (16, 4) = 64 blocks
    sdf_reduce_b<<<g2b, BLK2, 0, stream>>>(part2, pb);

    sdf_final<<<1, 64, 0, stream>>>(pb, out);
}